// Round 1
// baseline (909.810 us; speedup 1.0000x reference)
//
#include <hip/hip_runtime.h>
#include <stdint.h>

#define NE 8
#define TOKENS 8192
#define DIM 1024
#define HDIM 2048
#define N13 4096
#define CAP 17408      // 16384 assignments + 8*128 padding, multiple of 128
#define CAPT 136       // CAP/128 row tiles

typedef __bf16 bf16x8 __attribute__((ext_vector_type(8)));
typedef float f32x4 __attribute__((ext_vector_type(4)));

// ---- workspace layout (bytes, all 256-aligned) ----
#define OFF_XB    ((size_t)0)                       // bf16 x      [8192][1024]   16.8 MB
#define OFF_W13T  ((size_t)16777216)                // bf16 w13^T  [8][4096][1024] 67 MB
#define OFF_W2T   (OFF_W13T + (size_t)67108864)     // bf16 w2^T   [8][1024][2048] 33.5 MB
#define OFF_HID   (OFF_W2T + (size_t)33554432)      // bf16 hidden [CAP][2048]    71.3 MB
#define OFF_TIDX  (OFF_HID + (size_t)71303168)      // int  topk_idx [8192][2]
#define OFF_TW    (OFF_TIDX + (size_t)65536)        // f32  topk_w   [8192][2]
#define OFF_TOKID (OFF_TW + (size_t)65536)          // int  token_id [CAP]
#define OFF_ROWW  (OFF_TOKID + (size_t)69632)       // f32  row_w    [CAP]
#define OFF_CTRL  (OFF_ROWW + (size_t)69632)        // int  ctrl[32]: 0-7 counts, 8-15 cursor, 16-24 seg

__device__ __forceinline__ void async_copy16(const void* gsrc, void* ldst) {
  __builtin_amdgcn_global_load_lds(
      (__attribute__((address_space(1))) void*)((void*)(const_cast<void*>(gsrc))),
      (__attribute__((address_space(3))) void*)ldst, 16, 0, 0);
}

// ---------------- router: fp64 logits, top-2, softmax, counts; fused x->bf16 ----------------
__global__ __launch_bounds__(256) void router_kernel(
    const float* __restrict__ x, const float* __restrict__ rt,
    __bf16* __restrict__ xb, int* __restrict__ tidx, float* __restrict__ tw,
    int* __restrict__ ctrl) {
  int wave = blockIdx.x * 4 + (threadIdx.x >> 6);
  int l = threadIdx.x & 63;
  const float* xr = x + (size_t)wave * DIM;
  double acc[NE];
#pragma unroll
  for (int e = 0; e < NE; e++) acc[e] = 0.0;
#pragma unroll 4
  for (int i = 0; i < 16; i++) {
    int d = i * 64 + l;
    float xv = xr[d];
    xb[(size_t)wave * DIM + d] = (__bf16)xv;
    const float* rr = rt + (size_t)d * NE;
#pragma unroll
    for (int e = 0; e < NE; e++) acc[e] += (double)xv * (double)rr[e];
  }
#pragma unroll
  for (int e = 0; e < NE; e++) {
    double v = acc[e];
#pragma unroll
    for (int off = 32; off > 0; off >>= 1) v += __shfl_xor(v, off, 64);
    acc[e] = v;
  }
  if (l == 0) {
    int i0 = 0; double m0 = acc[0];
    for (int e = 1; e < NE; e++) if (acc[e] > m0) { m0 = acc[e]; i0 = e; }
    int i1 = -1; double m1 = -1.0e300;
    for (int e = 0; e < NE; e++) { if (e == i0) continue; if (acc[e] > m1) { m1 = acc[e]; i1 = e; } }
    double w0 = 1.0 / (1.0 + exp(m1 - m0));
    tidx[wave * 2 + 0] = i0; tidx[wave * 2 + 1] = i1;
    tw[wave * 2 + 0] = (float)w0; tw[wave * 2 + 1] = (float)(1.0 - w0);
    atomicAdd(&ctrl[i0], 1);
    atomicAdd(&ctrl[i1], 1);
  }
}

// ---------------- fp32 [e][K][N] -> bf16 [e][N][K] ----------------
__global__ __launch_bounds__(256) void transpose_kernel(
    const float* __restrict__ in, __bf16* __restrict__ outp, int K, int N) {
  __shared__ float tile[32][33];
  const size_t mat = (size_t)K * N;
  const float* ip = in + (size_t)blockIdx.z * mat;
  __bf16* op = outp + (size_t)blockIdx.z * mat;
  int n0 = blockIdx.x * 32, k0 = blockIdx.y * 32;
  int tx = threadIdx.x & 31, ty = threadIdx.x >> 5;
#pragma unroll
  for (int q = 0; q < 4; q++) {
    int yy = ty + q * 8;
    tile[yy][tx] = ip[(size_t)(k0 + yy) * N + n0 + tx];
  }
  __syncthreads();
#pragma unroll
  for (int q = 0; q < 4; q++) {
    int yy = ty + q * 8;
    op[(size_t)(n0 + yy) * K + k0 + tx] = (__bf16)tile[tx][yy];
  }
}

// ---------------- scan (pad segments to 128) + init padding rows ----------------
__global__ void scan_pad_kernel(int* __restrict__ ctrl, int* __restrict__ token_id,
                                float* __restrict__ row_w) {
  __shared__ int sseg[NE + 1];
  if (threadIdx.x == 0) {
    int s = 0;
    for (int e = 0; e < NE; e++) {
      sseg[e] = s; ctrl[16 + e] = s;
      int c = ctrl[e];
      s += (c + 127) & ~127;
    }
    sseg[NE] = s; ctrl[16 + NE] = s;
  }
  __syncthreads();
  for (int e = 0; e < NE; e++) {
    int c = ctrl[e];
    int pe = sseg[e + 1] - sseg[e];
    for (int i = c + (int)threadIdx.x; i < pe; i += 256) {
      token_id[sseg[e] + i] = -1;
      row_w[sseg[e] + i] = 0.f;
    }
  }
}

// ---------------- scatter assignments into grouped rows ----------------
__global__ __launch_bounds__(256) void scatter_kernel(
    const int* __restrict__ tidx, const float* __restrict__ tw,
    int* __restrict__ ctrl, int* __restrict__ token_id, float* __restrict__ row_w) {
  int a = blockIdx.x * 256 + threadIdx.x;  // 0..16383
  int e = tidx[a];
  int pos = ctrl[16 + e] + atomicAdd(&ctrl[8 + e], 1);
  token_id[pos] = a >> 1;
  row_w[pos] = tw[a];
}

// ---------------- GEMM1: hidden = silu(Xg @ W1) * (Xg @ W3), fused epilogue ----------------
// block: 128 rows x (64 gate + 64 up) cols, BK=32, 4 waves 2x2
__global__ __launch_bounds__(256) void gemm1_kernel(
    const __bf16* __restrict__ xb, const __bf16* __restrict__ w13t,
    const int* __restrict__ token_id, const int* __restrict__ ctrl,
    __bf16* __restrict__ hidden) {
  __shared__ __align__(16) __bf16 As[128 * 32];
  __shared__ __align__(16) __bf16 Bs[128 * 32];
  const int* seg = ctrl + 16;
  const int row_base = blockIdx.y * 128;
  if (row_base >= seg[NE]) return;
  int e = 0;
#pragma unroll
  for (int q = 1; q <= 7; q++) if (row_base >= seg[q]) e = q;

  const int g0 = blockIdx.x * 64;
  const int tid = threadIdx.x;
  const int l = tid & 63;
  const int wv = tid >> 6, wr = wv >> 1, wc = wv & 1;
  const int quad = l >> 4, lc = l & 15;

  // staging: 512 16B slots per tile; slot s -> row s>>2, k-offset (s&3)*8
  const int s0 = tid, s1 = tid + 256;
  const int am0 = s0 >> 2, am1 = s1 >> 2;
  const int koff = (tid & 3) * 8;
  int t0 = token_id[row_base + am0]; t0 = t0 < 0 ? 0 : t0;
  int t1 = token_id[row_base + am1]; t1 = t1 < 0 ? 0 : t1;
  const __bf16* ga0 = xb + (size_t)t0 * DIM + koff;
  const __bf16* ga1 = xb + (size_t)t1 * DIM + koff;
  const int gr0 = am0 < 64 ? (g0 + am0) : (2048 + g0 + am0 - 64);
  const int gr1 = am1 < 64 ? (g0 + am1) : (2048 + g0 + am1 - 64);
  const __bf16* wb = w13t + (size_t)e * N13 * DIM;
  const __bf16* gb0 = wb + (size_t)gr0 * DIM + koff;
  const __bf16* gb1 = wb + (size_t)gr1 * DIM + koff;

  const f32x4 fzero = {0.f, 0.f, 0.f, 0.f};
  f32x4 acc[4][4];
#pragma unroll
  for (int i = 0; i < 4; i++)
#pragma unroll
    for (int j = 0; j < 4; j++) acc[i][j] = fzero;

  const bf16x8* Af = (const bf16x8*)As;
  const bf16x8* Bf = (const bf16x8*)Bs;
  const int arow = wr * 64 + lc;
  const int brow0 = wc * 32 + lc;

  for (int kt = 0; kt < DIM; kt += 32) {
    async_copy16(ga0 + kt, As + (size_t)s0 * 8);
    async_copy16(ga1 + kt, As + (size_t)s1 * 8);
    async_copy16(gb0 + kt, Bs + (size_t)s0 * 8);
    async_copy16(gb1 + kt, Bs + (size_t)s1 * 8);
    __syncthreads();
    bf16x8 a[4], b[4];
#pragma unroll
    for (int i = 0; i < 4; i++) a[i] = Af[(arow + i * 16) * 4 + quad];
#pragma unroll
    for (int j = 0; j < 4; j++) {
      int br = (j < 2) ? (brow0 + j * 16) : (64 + brow0 + (j - 2) * 16);
      b[j] = Bf[br * 4 + quad];
    }
#pragma unroll
    for (int i = 0; i < 4; i++)
#pragma unroll
      for (int j = 0; j < 4; j++)
        acc[i][j] = __builtin_amdgcn_mfma_f32_16x16x32_bf16(a[i], b[j], acc[i][j], 0, 0, 0);
    __syncthreads();
  }

  // fused SwiGLU epilogue: acc[i][0..1]=gate cols, acc[i][2..3]=up cols (same lane,row,col)
#pragma unroll
  for (int i = 0; i < 4; i++) {
#pragma unroll
    for (int jj = 0; jj < 2; jj++) {
      f32x4 g = acc[i][jj];
      f32x4 u = acc[i][jj + 2];
      int col = g0 + wc * 32 + jj * 16 + lc;
#pragma unroll
      for (int r = 0; r < 4; r++) {
        int row = row_base + wr * 64 + i * 16 + quad * 4 + r;
        float gv = g[r], uv = u[r];
        float h = (gv / (1.0f + __expf(-gv))) * uv;
        hidden[(size_t)row * HDIM + col] = (__bf16)h;
      }
    }
  }
}

// ---------------- GEMM2: out[tok] += w * (hidden @ W2) ----------------
__global__ __launch_bounds__(256) void gemm2_kernel(
    const __bf16* __restrict__ hidden, const __bf16* __restrict__ w2t,
    const int* __restrict__ token_id, const float* __restrict__ row_w,
    const int* __restrict__ ctrl, float* __restrict__ out) {
  __shared__ __align__(16) __bf16 As[128 * 32];
  __shared__ __align__(16) __bf16 Bs[128 * 32];
  const int* seg = ctrl + 16;
  const int row_base = blockIdx.y * 128;
  if (row_base >= seg[NE]) return;
  int e = 0;
#pragma unroll
  for (int q = 1; q <= 7; q++) if (row_base >= seg[q]) e = q;

  const int bn0 = blockIdx.x * 128;
  const int tid = threadIdx.x;
  const int l = tid & 63;
  const int wv = tid >> 6, wr = wv >> 1, wc = wv & 1;
  const int quad = l >> 4, lc = l & 15;

  const int s0 = tid, s1 = tid + 256;
  const int am0 = s0 >> 2, am1 = s1 >> 2;
  const int koff = (tid & 3) * 8;
  const __bf16* ga0 = hidden + (size_t)(row_base + am0) * HDIM + koff;
  const __bf16* ga1 = hidden + (size_t)(row_base + am1) * HDIM + koff;
  const __bf16* wb = w2t + (size_t)e * DIM * HDIM;
  const __bf16* gb0 = wb + (size_t)(bn0 + am0) * HDIM + koff;
  const __bf16* gb1 = wb + (size_t)(bn0 + am1) * HDIM + koff;

  const f32x4 fzero = {0.f, 0.f, 0.f, 0.f};
  f32x4 acc[4][4];
#pragma unroll
  for (int i = 0; i < 4; i++)
#pragma unroll
    for (int j = 0; j < 4; j++) acc[i][j] = fzero;

  const bf16x8* Af = (const bf16x8*)As;
  const bf16x8* Bf = (const bf16x8*)Bs;
  const int arow = wr * 64 + lc;
  const int brow = wc * 64 + lc;

  for (int kt = 0; kt < HDIM; kt += 32) {
    async_copy16(ga0 + kt, As + (size_t)s0 * 8);
    async_copy16(ga1 + kt, As + (size_t)s1 * 8);
    async_copy16(gb0 + kt, Bs + (size_t)s0 * 8);
    async_copy16(gb1 + kt, Bs + (size_t)s1 * 8);
    __syncthreads();
    bf16x8 a[4], b[4];
#pragma unroll
    for (int i = 0; i < 4; i++) a[i] = Af[(arow + i * 16) * 4 + quad];
#pragma unroll
    for (int j = 0; j < 4; j++) b[j] = Bf[(brow + j * 16) * 4 + quad];
#pragma unroll
    for (int i = 0; i < 4; i++)
#pragma unroll
      for (int j = 0; j < 4; j++)
        acc[i][j] = __builtin_amdgcn_mfma_f32_16x16x32_bf16(a[i], b[j], acc[i][j], 0, 0, 0);
    __syncthreads();
  }

#pragma unroll
  for (int i = 0; i < 4; i++) {
    int rbase = row_base + wr * 64 + i * 16 + quad * 4;
    int tok[4]; float wt[4];
#pragma unroll
    for (int r = 0; r < 4; r++) { tok[r] = token_id[rbase + r]; wt[r] = row_w[rbase + r]; }
#pragma unroll
    for (int j = 0; j < 4; j++) {
      int col = bn0 + wc * 64 + j * 16 + lc;
#pragma unroll
      for (int r = 0; r < 4; r++) {
        if (tok[r] >= 0)
          atomicAdd(&out[(size_t)tok[r] * DIM + col], acc[i][j][r] * wt[r]);
      }
    }
  }
}

extern "C" void kernel_launch(void* const* d_in, const int* in_sizes, int n_in,
                              void* d_out, int out_size, void* d_ws, size_t ws_size,
                              hipStream_t stream) {
  const float* x   = (const float*)d_in[0];
  const float* rt  = (const float*)d_in[1];
  const float* w13 = (const float*)d_in[2];
  const float* w2  = (const float*)d_in[3];
  float* out = (float*)d_out;
  char* ws = (char*)d_ws;

  __bf16* xb      = (__bf16*)(ws + OFF_XB);
  __bf16* w13t    = (__bf16*)(ws + OFF_W13T);
  __bf16* w2t     = (__bf16*)(ws + OFF_W2T);
  __bf16* hidden  = (__bf16*)(ws + OFF_HID);
  int*    tidx    = (int*)(ws + OFF_TIDX);
  float*  tw      = (float*)(ws + OFF_TW);
  int*    tokid   = (int*)(ws + OFF_TOKID);
  float*  roww    = (float*)(ws + OFF_ROWW);
  int*    ctrl    = (int*)(ws + OFF_CTRL);

  hipMemsetAsync(out, 0, (size_t)TOKENS * DIM * sizeof(float), stream);
  hipMemsetAsync(ctrl, 0, 128, stream);

  hipLaunchKernelGGL(router_kernel, dim3(TOKENS / 4), dim3(256), 0, stream,
                     x, rt, xb, tidx, tw, ctrl);
  hipLaunchKernelGGL(transpose_kernel, dim3(N13 / 32, DIM / 32, NE), dim3(256), 0, stream,
                     w13, w13t, DIM, N13);
  hipLaunchKernelGGL(transpose_kernel, dim3(DIM / 32, HDIM / 32, NE), dim3(256), 0, stream,
                     w2, w2t, HDIM, DIM);
  hipLaunchKernelGGL(scan_pad_kernel, dim3(1), dim3(256), 0, stream, ctrl, tokid, roww);
  hipLaunchKernelGGL(scatter_kernel, dim3(TOKENS * 2 / 256), dim3(256), 0, stream,
                     tidx, tw, ctrl, tokid, roww);
  hipLaunchKernelGGL(gemm1_kernel, dim3(HDIM / 64, CAPT), dim3(256), 0, stream,
                     xb, w13t, tokid, ctrl, hidden);
  hipLaunchKernelGGL(gemm2_kernel, dim3(DIM / 128, CAPT), dim3(256), 0, stream,
                     hidden, w2t, tokid, roww, ctrl, out);
}

// Round 2
// 732.121 us; speedup vs baseline: 1.2427x; 1.2427x over previous
//
#include <hip/hip_runtime.h>
#include <stdint.h>

#define NE 8
#define TOKENS 8192
#define DIM 1024
#define HDIM 2048
#define N13 4096
#define CAP 17408      // 16384 assignments + 8*128 padding, multiple of 128
#define CAPT 136       // CAP/128 row tiles

typedef __bf16 bf16x8 __attribute__((ext_vector_type(8)));
typedef __bf16 bf16x4_t __attribute__((ext_vector_type(4)));
typedef float f32x4 __attribute__((ext_vector_type(4)));

// ---- workspace layout (bytes, all 256-aligned) ----
#define OFF_XB    ((size_t)0)                       // bf16 x      [8192][1024]   16.8 MB
#define OFF_W13T  ((size_t)16777216)                // bf16 w13^T  [8][4096][1024] 67 MB
#define OFF_W2T   (OFF_W13T + (size_t)67108864)     // bf16 w2^T   [8][1024][2048] 33.5 MB
#define OFF_HID   (OFF_W2T + (size_t)33554432)      // bf16 hidden [CAP][2048]    71.3 MB
#define OFF_TIDX  (OFF_HID + (size_t)71303168)      // int  topk_idx [8192][2]
#define OFF_TW    (OFF_TIDX + (size_t)65536)        // f32  topk_w   [8192][2]
#define OFF_TOKID (OFF_TW + (size_t)65536)          // int  token_id [CAP]
#define OFF_ROWW  (OFF_TOKID + (size_t)69632)       // f32  row_w    [CAP]
#define OFF_CTRL  (OFF_ROWW + (size_t)69632)        // int  ctrl[32]: 0-7 counts, 8-15 cursor, 16-24 seg

__device__ __forceinline__ void async_copy16(const void* gsrc, void* ldst) {
  __builtin_amdgcn_global_load_lds(
      (__attribute__((address_space(1))) void*)((void*)(const_cast<void*>(gsrc))),
      (__attribute__((address_space(3))) void*)ldst, 16, 0, 0);
}

// ---------------- router v2: block-per-token, fp64 logits, top-2, softmax ----------------
// thread = (e = tid&7, ds = tid>>3).  3 fp64 shuffles + tiny LDS reduce.  No atomics.
__global__ __launch_bounds__(256) void router_kernel(
    const float* __restrict__ x, const float* __restrict__ rt,
    __bf16* __restrict__ xb, int* __restrict__ tidx, float* __restrict__ tw) {
  __shared__ __align__(16) float xrow[DIM];
  __shared__ double red[4][NE];
  const int t = blockIdx.x;
  const int tid = threadIdx.x;
  const int e = tid & 7, ds = tid >> 3;
  const int w = tid >> 6, l = tid & 63;

  // stage x row (coalesced float4) + fused bf16 cast to xb
  f32x4 v = ((const f32x4*)(x + (size_t)t * DIM))[tid];
  ((f32x4*)xrow)[tid] = v;
  bf16x4_t h;
  h[0] = (__bf16)v[0]; h[1] = (__bf16)v[1]; h[2] = (__bf16)v[2]; h[3] = (__bf16)v[3];
  ((bf16x4_t*)(xb + (size_t)t * DIM))[tid] = h;
  __syncthreads();

  double acc = 0.0;
#pragma unroll
  for (int k = 0; k < 32; k++) {
    int kk = (k + ds) & 31;           // rotate -> conflict-free LDS banks
    int d = ds * 32 + kk;
    acc += (double)xrow[d] * (double)rt[(size_t)d * NE + e];
  }
  // reduce over ds within wave: lane = ds_local*8 + e, ds bits are lane[5:3]
  acc += __shfl_xor(acc, 8, 64);
  acc += __shfl_xor(acc, 16, 64);
  acc += __shfl_xor(acc, 32, 64);
  if ((l >> 3) == 0) red[w][e] = acc;
  __syncthreads();
  if (tid == 0) {
    double lg[NE];
#pragma unroll
    for (int q = 0; q < NE; q++) lg[q] = red[0][q] + red[1][q] + red[2][q] + red[3][q];
    int i0 = 0; double m0 = lg[0];
    for (int q = 1; q < NE; q++) if (lg[q] > m0) { m0 = lg[q]; i0 = q; }
    int i1 = -1; double m1 = -1.0e300;
    for (int q = 0; q < NE; q++) { if (q == i0) continue; if (lg[q] > m1) { m1 = lg[q]; i1 = q; } }
    double w0 = 1.0 / (1.0 + exp(m1 - m0));
    tidx[t * 2 + 0] = i0; tidx[t * 2 + 1] = i1;
    tw[t * 2 + 0] = (float)w0; tw[t * 2 + 1] = (float)(1.0 - w0);
  }
}

// ---------------- per-expert counts: LDS histogram, 8 global atomics/block ----------------
__global__ __launch_bounds__(256) void histo_kernel(const int* __restrict__ tidx,
                                                    int* __restrict__ ctrl) {
  __shared__ int cnt[NE];
  if (threadIdx.x < NE) cnt[threadIdx.x] = 0;
  __syncthreads();
  int i = blockIdx.x * 256 + threadIdx.x;  // 0..16383
  atomicAdd(&cnt[tidx[i]], 1);
  __syncthreads();
  if (threadIdx.x < NE) atomicAdd(&ctrl[threadIdx.x], cnt[threadIdx.x]);
}

// ---------------- fp32 [e][K][N] -> bf16 [e][N][K] ----------------
__global__ __launch_bounds__(256) void transpose_kernel(
    const float* __restrict__ in, __bf16* __restrict__ outp, int K, int N) {
  __shared__ float tile[32][33];
  const size_t mat = (size_t)K * N;
  const float* ip = in + (size_t)blockIdx.z * mat;
  __bf16* op = outp + (size_t)blockIdx.z * mat;
  int n0 = blockIdx.x * 32, k0 = blockIdx.y * 32;
  int tx = threadIdx.x & 31, ty = threadIdx.x >> 5;
#pragma unroll
  for (int q = 0; q < 4; q++) {
    int yy = ty + q * 8;
    tile[yy][tx] = ip[(size_t)(k0 + yy) * N + n0 + tx];
  }
  __syncthreads();
#pragma unroll
  for (int q = 0; q < 4; q++) {
    int yy = ty + q * 8;
    op[(size_t)(n0 + yy) * K + k0 + tx] = (__bf16)tile[tx][yy];
  }
}

// ---------------- scan (pad segments to 128) + init padding rows ----------------
__global__ void scan_pad_kernel(int* __restrict__ ctrl, int* __restrict__ token_id,
                                float* __restrict__ row_w) {
  __shared__ int sseg[NE + 1];
  if (threadIdx.x == 0) {
    int s = 0;
    for (int e = 0; e < NE; e++) {
      sseg[e] = s; ctrl[16 + e] = s;
      int c = ctrl[e];
      s += (c + 127) & ~127;
    }
    sseg[NE] = s; ctrl[16 + NE] = s;
  }
  __syncthreads();
  for (int e = 0; e < NE; e++) {
    int c = ctrl[e];
    int pe = sseg[e + 1] - sseg[e];
    for (int i = c + (int)threadIdx.x; i < pe; i += 256) {
      token_id[sseg[e] + i] = -1;
      row_w[sseg[e] + i] = 0.f;
    }
  }
}

// ---------------- scatter assignments into grouped rows ----------------
__global__ __launch_bounds__(256) void scatter_kernel(
    const int* __restrict__ tidx, const float* __restrict__ tw,
    int* __restrict__ ctrl, int* __restrict__ token_id, float* __restrict__ row_w) {
  int a = blockIdx.x * 256 + threadIdx.x;  // 0..16383
  int e = tidx[a];
  int pos = ctrl[16 + e] + atomicAdd(&ctrl[8 + e], 1);
  token_id[pos] = a >> 1;
  row_w[pos] = tw[a];
}

// ---------------- GEMM1: hidden = silu(Xg @ W1) * (Xg @ W3), fused epilogue ----------------
// block: 128 rows x (64 gate + 64 up) cols, BK=32, 4 waves 2x2
__global__ __launch_bounds__(256) void gemm1_kernel(
    const __bf16* __restrict__ xb, const __bf16* __restrict__ w13t,
    const int* __restrict__ token_id, const int* __restrict__ ctrl,
    __bf16* __restrict__ hidden) {
  __shared__ __align__(16) __bf16 As[128 * 32];
  __shared__ __align__(16) __bf16 Bs[128 * 32];
  const int* seg = ctrl + 16;
  const int row_base = blockIdx.y * 128;
  if (row_base >= seg[NE]) return;
  int e = 0;
#pragma unroll
  for (int q = 1; q <= 7; q++) if (row_base >= seg[q]) e = q;

  const int g0 = blockIdx.x * 64;
  const int tid = threadIdx.x;
  const int l = tid & 63;
  const int wv = tid >> 6, wr = wv >> 1, wc = wv & 1;
  const int quad = l >> 4, lc = l & 15;

  const int s0 = tid, s1 = tid + 256;
  const int am0 = s0 >> 2, am1 = s1 >> 2;
  const int koff = (tid & 3) * 8;
  int t0 = token_id[row_base + am0]; t0 = t0 < 0 ? 0 : t0;
  int t1 = token_id[row_base + am1]; t1 = t1 < 0 ? 0 : t1;
  const __bf16* ga0 = xb + (size_t)t0 * DIM + koff;
  const __bf16* ga1 = xb + (size_t)t1 * DIM + koff;
  const int gr0 = am0 < 64 ? (g0 + am0) : (2048 + g0 + am0 - 64);
  const int gr1 = am1 < 64 ? (g0 + am1) : (2048 + g0 + am1 - 64);
  const __bf16* wb = w13t + (size_t)e * N13 * DIM;
  const __bf16* gb0 = wb + (size_t)gr0 * DIM + koff;
  const __bf16* gb1 = wb + (size_t)gr1 * DIM + koff;

  const f32x4 fzero = {0.f, 0.f, 0.f, 0.f};
  f32x4 acc[4][4];
#pragma unroll
  for (int i = 0; i < 4; i++)
#pragma unroll
    for (int j = 0; j < 4; j++) acc[i][j] = fzero;

  const bf16x8* Af = (const bf16x8*)As;
  const bf16x8* Bf = (const bf16x8*)Bs;
  const int arow = wr * 64 + lc;
  const int brow0 = wc * 32 + lc;

  for (int kt = 0; kt < DIM; kt += 32) {
    async_copy16(ga0 + kt, As + (size_t)s0 * 8);
    async_copy16(ga1 + kt, As + (size_t)s1 * 8);
    async_copy16(gb0 + kt, Bs + (size_t)s0 * 8);
    async_copy16(gb1 + kt, Bs + (size_t)s1 * 8);
    __syncthreads();
    bf16x8 a[4], b[4];
#pragma unroll
    for (int i = 0; i < 4; i++) a[i] = Af[(arow + i * 16) * 4 + quad];
#pragma unroll
    for (int j = 0; j < 4; j++) {
      int br = (j < 2) ? (brow0 + j * 16) : (64 + brow0 + (j - 2) * 16);
      b[j] = Bf[br * 4 + quad];
    }
#pragma unroll
    for (int i = 0; i < 4; i++)
#pragma unroll
      for (int j = 0; j < 4; j++)
        acc[i][j] = __builtin_amdgcn_mfma_f32_16x16x32_bf16(a[i], b[j], acc[i][j], 0, 0, 0);
    __syncthreads();
  }

  // fused SwiGLU epilogue: acc[i][0..1]=gate cols, acc[i][2..3]=up cols
#pragma unroll
  for (int i = 0; i < 4; i++) {
#pragma unroll
    for (int jj = 0; jj < 2; jj++) {
      f32x4 g = acc[i][jj];
      f32x4 u = acc[i][jj + 2];
      int col = g0 + wc * 32 + jj * 16 + lc;
#pragma unroll
      for (int r = 0; r < 4; r++) {
        int row = row_base + wr * 64 + i * 16 + quad * 4 + r;
        float gv = g[r], uv = u[r];
        float hh = (gv / (1.0f + __expf(-gv))) * uv;
        hidden[(size_t)row * HDIM + col] = (__bf16)hh;
      }
    }
  }
}

// ---------------- GEMM2: out[tok] += w * (hidden @ W2) ----------------
__global__ __launch_bounds__(256) void gemm2_kernel(
    const __bf16* __restrict__ hidden, const __bf16* __restrict__ w2t,
    const int* __restrict__ token_id, const float* __restrict__ row_w,
    const int* __restrict__ ctrl, float* __restrict__ out) {
  __shared__ __align__(16) __bf16 As[128 * 32];
  __shared__ __align__(16) __bf16 Bs[128 * 32];
  const int* seg = ctrl + 16;
  const int row_base = blockIdx.y * 128;
  if (row_base >= seg[NE]) return;
  int e = 0;
#pragma unroll
  for (int q = 1; q <= 7; q++) if (row_base >= seg[q]) e = q;

  const int bn0 = blockIdx.x * 128;
  const int tid = threadIdx.x;
  const int l = tid & 63;
  const int wv = tid >> 6, wr = wv >> 1, wc = wv & 1;
  const int quad = l >> 4, lc = l & 15;

  const int s0 = tid, s1 = tid + 256;
  const int am0 = s0 >> 2, am1 = s1 >> 2;
  const int koff = (tid & 3) * 8;
  const __bf16* ga0 = hidden + (size_t)(row_base + am0) * HDIM + koff;
  const __bf16* ga1 = hidden + (size_t)(row_base + am1) * HDIM + koff;
  const __bf16* wb = w2t + (size_t)e * DIM * HDIM;
  const __bf16* gb0 = wb + (size_t)(bn0 + am0) * HDIM + koff;
  const __bf16* gb1 = wb + (size_t)(bn0 + am1) * HDIM + koff;

  const f32x4 fzero = {0.f, 0.f, 0.f, 0.f};
  f32x4 acc[4][4];
#pragma unroll
  for (int i = 0; i < 4; i++)
#pragma unroll
    for (int j = 0; j < 4; j++) acc[i][j] = fzero;

  const bf16x8* Af = (const bf16x8*)As;
  const bf16x8* Bf = (const bf16x8*)Bs;
  const int arow = wr * 64 + lc;
  const int brow = wc * 64 + lc;

  for (int kt = 0; kt < HDIM; kt += 32) {
    async_copy16(ga0 + kt, As + (size_t)s0 * 8);
    async_copy16(ga1 + kt, As + (size_t)s1 * 8);
    async_copy16(gb0 + kt, Bs + (size_t)s0 * 8);
    async_copy16(gb1 + kt, Bs + (size_t)s1 * 8);
    __syncthreads();
    bf16x8 a[4], b[4];
#pragma unroll
    for (int i = 0; i < 4; i++) a[i] = Af[(arow + i * 16) * 4 + quad];
#pragma unroll
    for (int j = 0; j < 4; j++) b[j] = Bf[(brow + j * 16) * 4 + quad];
#pragma unroll
    for (int i = 0; i < 4; i++)
#pragma unroll
      for (int j = 0; j < 4; j++)
        acc[i][j] = __builtin_amdgcn_mfma_f32_16x16x32_bf16(a[i], b[j], acc[i][j], 0, 0, 0);
    __syncthreads();
  }

#pragma unroll
  for (int i = 0; i < 4; i++) {
    int rbase = row_base + wr * 64 + i * 16 + quad * 4;
    int tok[4]; float wt[4];
#pragma unroll
    for (int r = 0; r < 4; r++) { tok[r] = token_id[rbase + r]; wt[r] = row_w[rbase + r]; }
#pragma unroll
    for (int j = 0; j < 4; j++) {
      int col = bn0 + wc * 64 + j * 16 + lc;
#pragma unroll
      for (int r = 0; r < 4; r++) {
        if (tok[r] >= 0)
          atomicAdd(&out[(size_t)tok[r] * DIM + col], acc[i][j][r] * wt[r]);
      }
    }
  }
}

extern "C" void kernel_launch(void* const* d_in, const int* in_sizes, int n_in,
                              void* d_out, int out_size, void* d_ws, size_t ws_size,
                              hipStream_t stream) {
  const float* x   = (const float*)d_in[0];
  const float* rt  = (const float*)d_in[1];
  const float* w13 = (const float*)d_in[2];
  const float* w2  = (const float*)d_in[3];
  float* out = (float*)d_out;
  char* ws = (char*)d_ws;

  __bf16* xb      = (__bf16*)(ws + OFF_XB);
  __bf16* w13t    = (__bf16*)(ws + OFF_W13T);
  __bf16* w2t     = (__bf16*)(ws + OFF_W2T);
  __bf16* hidden  = (__bf16*)(ws + OFF_HID);
  int*    tidx    = (int*)(ws + OFF_TIDX);
  float*  tw      = (float*)(ws + OFF_TW);
  int*    tokid   = (int*)(ws + OFF_TOKID);
  float*  roww    = (float*)(ws + OFF_ROWW);
  int*    ctrl    = (int*)(ws + OFF_CTRL);

  hipMemsetAsync(out, 0, (size_t)TOKENS * DIM * sizeof(float), stream);
  hipMemsetAsync(ctrl, 0, 128, stream);

  hipLaunchKernelGGL(router_kernel, dim3(TOKENS), dim3(256), 0, stream,
                     x, rt, xb, tidx, tw);
  hipLaunchKernelGGL(transpose_kernel, dim3(N13 / 32, DIM / 32, NE), dim3(256), 0, stream,
                     w13, w13t, DIM, N13);
  hipLaunchKernelGGL(transpose_kernel, dim3(DIM / 32, HDIM / 32, NE), dim3(256), 0, stream,
                     w2, w2t, HDIM, DIM);
  hipLaunchKernelGGL(histo_kernel, dim3(TOKENS * 2 / 256), dim3(256), 0, stream, tidx, ctrl);
  hipLaunchKernelGGL(scan_pad_kernel, dim3(1), dim3(256), 0, stream, ctrl, tokid, roww);
  hipLaunchKernelGGL(scatter_kernel, dim3(TOKENS * 2 / 256), dim3(256), 0, stream,
                     tidx, tw, ctrl, tokid, roww);
  hipLaunchKernelGGL(gemm1_kernel, dim3(HDIM / 64, CAPT), dim3(256), 0, stream,
                     xb, w13t, tokid, ctrl, hidden);
  hipLaunchKernelGGL(gemm2_kernel, dim3(DIM / 128, CAPT), dim3(256), 0, stream,
                     hidden, w2t, tokid, roww, ctrl, out);
}

// Round 3
// 592.066 us; speedup vs baseline: 1.5367x; 1.2366x over previous
//
#include <hip/hip_runtime.h>
#include <stdint.h>

#define NE 8
#define TOKENS 8192
#define DIM 1024
#define HDIM 2048
#define N13 4096
#define CAP 17408      // 16384 assignments + 8*128 padding, multiple of 128
#define CAPT 136       // CAP/128 row tiles

typedef __bf16 bf16x8 __attribute__((ext_vector_type(8)));
typedef __bf16 bf16x4_t __attribute__((ext_vector_type(4)));
typedef float f32x4 __attribute__((ext_vector_type(4)));

// ---- workspace layout (bytes) ----
#define OFF_XB    ((size_t)0)                                  // bf16 [8192][1024]
#define OFF_W13T  (OFF_XB    + (size_t)TOKENS * DIM * 2)       // bf16 [8][4096][1024]
#define OFF_W2T   (OFF_W13T  + (size_t)NE * N13 * DIM * 2)     // bf16 [8][1024][2048]
#define OFF_HID   (OFF_W2T   + (size_t)NE * DIM * HDIM * 2)    // bf16 [CAP][2048]
#define OFF_DISP  (OFF_HID   + (size_t)CAP * HDIM * 2)         // bf16 [CAP][1024]
#define OFF_TIDX  (OFF_DISP  + (size_t)CAP * DIM * 2)          // int  [8192][2]
#define OFF_TW    (OFF_TIDX  + (size_t)TOKENS * 2 * 4)         // f32  [8192][2]
#define OFF_POS   (OFF_TW    + (size_t)TOKENS * 2 * 4)         // int  [8192][2]
#define OFF_TOKID (OFF_POS   + (size_t)TOKENS * 2 * 4)         // int  [CAP]
#define OFF_ROWW  (OFF_TOKID + (size_t)CAP * 4)                // f32  [CAP]
#define OFF_CTRL  (OFF_ROWW  + (size_t)CAP * 4)                // int  ctrl[32]

__device__ __forceinline__ void async_copy16(const void* gsrc, void* ldst) {
  __builtin_amdgcn_global_load_lds(
      (__attribute__((address_space(1))) void*)((void*)(const_cast<void*>(gsrc))),
      (__attribute__((address_space(3))) void*)ldst, 16, 0, 0);
}

// ---------------- router: block-per-token, fp64 logits, top-2, softmax ----------------
__global__ __launch_bounds__(256) void router_kernel(
    const float* __restrict__ x, const float* __restrict__ rt,
    __bf16* __restrict__ xb, int* __restrict__ tidx, float* __restrict__ tw) {
  __shared__ __align__(16) float xrow[DIM];
  __shared__ double red[4][NE];
  const int t = blockIdx.x;
  const int tid = threadIdx.x;
  const int e = tid & 7, ds = tid >> 3;
  const int w = tid >> 6, l = tid & 63;

  f32x4 v = ((const f32x4*)(x + (size_t)t * DIM))[tid];
  ((f32x4*)xrow)[tid] = v;
  bf16x4_t h;
  h[0] = (__bf16)v[0]; h[1] = (__bf16)v[1]; h[2] = (__bf16)v[2]; h[3] = (__bf16)v[3];
  ((bf16x4_t*)(xb + (size_t)t * DIM))[tid] = h;
  __syncthreads();

  double acc = 0.0;
#pragma unroll
  for (int k = 0; k < 32; k++) {
    int kk = (k + ds) & 31;
    int d = ds * 32 + kk;
    acc += (double)xrow[d] * (double)rt[(size_t)d * NE + e];
  }
  acc += __shfl_xor(acc, 8, 64);
  acc += __shfl_xor(acc, 16, 64);
  acc += __shfl_xor(acc, 32, 64);
  if ((l >> 3) == 0) red[w][e] = acc;
  __syncthreads();
  if (tid == 0) {
    double lg[NE];
#pragma unroll
    for (int q = 0; q < NE; q++) lg[q] = red[0][q] + red[1][q] + red[2][q] + red[3][q];
    int i0 = 0; double m0 = lg[0];
    for (int q = 1; q < NE; q++) if (lg[q] > m0) { m0 = lg[q]; i0 = q; }
    int i1 = -1; double m1 = -1.0e300;
    for (int q = 0; q < NE; q++) { if (q == i0) continue; if (lg[q] > m1) { m1 = lg[q]; i1 = q; } }
    double w0 = 1.0 / (1.0 + exp(m1 - m0));
    tidx[t * 2 + 0] = i0; tidx[t * 2 + 1] = i1;
    tw[t * 2 + 0] = (float)w0; tw[t * 2 + 1] = (float)(1.0 - w0);
  }
}

// ---------------- per-expert counts ----------------
__global__ __launch_bounds__(256) void histo_kernel(const int* __restrict__ tidx,
                                                    int* __restrict__ ctrl) {
  __shared__ int cnt[NE];
  if (threadIdx.x < NE) cnt[threadIdx.x] = 0;
  __syncthreads();
  int i = blockIdx.x * 256 + threadIdx.x;
  atomicAdd(&cnt[tidx[i]], 1);
  __syncthreads();
  if (threadIdx.x < NE) atomicAdd(&ctrl[threadIdx.x], cnt[threadIdx.x]);
}

// ---------------- transpose v2: fp32 [e][K][N] -> bf16 [e][N][K], no LDS ----------------
// block covers 64 N x 32 K.  lane: kq = tid&3 (8 K each), n = tid>>2.
// loads: 8 coalesced dword gathers; store: one 16B bf16x8.
__global__ __launch_bounds__(256) void transpose_kernel(
    const float* __restrict__ in, __bf16* __restrict__ outp, int K, int N) {
  const size_t mat = (size_t)K * N;
  const float* ip = in + (size_t)blockIdx.z * mat;
  __bf16* op = outp + (size_t)blockIdx.z * mat;
  const int tid = threadIdx.x;
  const int n = blockIdx.x * 64 + (tid >> 2);
  const int kb = blockIdx.y * 32 + (tid & 3) * 8;
  bf16x8 o;
#pragma unroll
  for (int j = 0; j < 8; j++)
    o[j] = (__bf16)ip[(size_t)(kb + j) * N + n];
  *(bf16x8*)(op + (size_t)n * K + kb) = o;
}

// ---------------- scan (pad segments to 128) + init padding rows ----------------
__global__ void scan_pad_kernel(int* __restrict__ ctrl, int* __restrict__ token_id,
                                float* __restrict__ row_w) {
  __shared__ int sseg[NE + 1];
  if (threadIdx.x == 0) {
    int s = 0;
    for (int e = 0; e < NE; e++) {
      sseg[e] = s; ctrl[16 + e] = s;
      int c = ctrl[e];
      s += (c + 127) & ~127;
    }
    sseg[NE] = s; ctrl[16 + NE] = s;
  }
  __syncthreads();
  for (int e = 0; e < NE; e++) {
    int c = ctrl[e];
    int pe = sseg[e + 1] - sseg[e];
    for (int i = c + (int)threadIdx.x; i < pe; i += 256) {
      token_id[sseg[e] + i] = -1;
      row_w[sseg[e] + i] = 0.f;
    }
  }
}

// ---------------- scatter v2: LDS rank aggregation, 8 global atomics/block ----------------
__global__ __launch_bounds__(256) void scatter_kernel(
    const int* __restrict__ tidx, const float* __restrict__ tw,
    int* __restrict__ ctrl, int* __restrict__ token_id, float* __restrict__ row_w,
    int* __restrict__ pos_of) {
  __shared__ int lcnt[NE];
  __shared__ int lbase[NE];
  const int tid = threadIdx.x;
  if (tid < NE) lcnt[tid] = 0;
  __syncthreads();
  int a = blockIdx.x * 256 + tid;
  int e = tidx[a];
  int rank = atomicAdd(&lcnt[e], 1);
  __syncthreads();
  if (tid < NE) lbase[tid] = atomicAdd(&ctrl[8 + tid], lcnt[tid]);
  __syncthreads();
  int pos = ctrl[16 + e] + lbase[e] + rank;
  token_id[pos] = a >> 1;
  row_w[pos] = tw[a];
  pos_of[a] = pos;
}

// ---------------- GEMM1: hidden = silu(Xg @ W1) * (Xg @ W3), fused epilogue ----------------
__global__ __launch_bounds__(256) void gemm1_kernel(
    const __bf16* __restrict__ xb, const __bf16* __restrict__ w13t,
    const int* __restrict__ token_id, const int* __restrict__ ctrl,
    __bf16* __restrict__ hidden) {
  __shared__ __align__(16) __bf16 As[128 * 32];
  __shared__ __align__(16) __bf16 Bs[128 * 32];
  const int* seg = ctrl + 16;
  const int row_base = blockIdx.y * 128;
  if (row_base >= seg[NE]) return;
  int e = 0;
#pragma unroll
  for (int q = 1; q <= 7; q++) if (row_base >= seg[q]) e = q;

  const int g0 = blockIdx.x * 64;
  const int tid = threadIdx.x;
  const int l = tid & 63;
  const int wv = tid >> 6, wr = wv >> 1, wc = wv & 1;
  const int quad = l >> 4, lc = l & 15;

  const int s0 = tid, s1 = tid + 256;
  const int am0 = s0 >> 2, am1 = s1 >> 2;
  const int koff = (tid & 3) * 8;
  int t0 = token_id[row_base + am0]; t0 = t0 < 0 ? 0 : t0;
  int t1 = token_id[row_base + am1]; t1 = t1 < 0 ? 0 : t1;
  const __bf16* ga0 = xb + (size_t)t0 * DIM + koff;
  const __bf16* ga1 = xb + (size_t)t1 * DIM + koff;
  const int gr0 = am0 < 64 ? (g0 + am0) : (2048 + g0 + am0 - 64);
  const int gr1 = am1 < 64 ? (g0 + am1) : (2048 + g0 + am1 - 64);
  const __bf16* wb = w13t + (size_t)e * N13 * DIM;
  const __bf16* gb0 = wb + (size_t)gr0 * DIM + koff;
  const __bf16* gb1 = wb + (size_t)gr1 * DIM + koff;

  const f32x4 fzero = {0.f, 0.f, 0.f, 0.f};
  f32x4 acc[4][4];
#pragma unroll
  for (int i = 0; i < 4; i++)
#pragma unroll
    for (int j = 0; j < 4; j++) acc[i][j] = fzero;

  const bf16x8* Af = (const bf16x8*)As;
  const bf16x8* Bf = (const bf16x8*)Bs;
  const int arow = wr * 64 + lc;
  const int brow0 = wc * 32 + lc;

  for (int kt = 0; kt < DIM; kt += 32) {
    async_copy16(ga0 + kt, As + (size_t)s0 * 8);
    async_copy16(ga1 + kt, As + (size_t)s1 * 8);
    async_copy16(gb0 + kt, Bs + (size_t)s0 * 8);
    async_copy16(gb1 + kt, Bs + (size_t)s1 * 8);
    __syncthreads();
    bf16x8 a[4], b[4];
#pragma unroll
    for (int i = 0; i < 4; i++) a[i] = Af[(arow + i * 16) * 4 + quad];
#pragma unroll
    for (int j = 0; j < 4; j++) {
      int br = (j < 2) ? (brow0 + j * 16) : (64 + brow0 + (j - 2) * 16);
      b[j] = Bf[br * 4 + quad];
    }
#pragma unroll
    for (int i = 0; i < 4; i++)
#pragma unroll
      for (int j = 0; j < 4; j++)
        acc[i][j] = __builtin_amdgcn_mfma_f32_16x16x32_bf16(a[i], b[j], acc[i][j], 0, 0, 0);
    __syncthreads();
  }

#pragma unroll
  for (int i = 0; i < 4; i++) {
#pragma unroll
    for (int jj = 0; jj < 2; jj++) {
      f32x4 g = acc[i][jj];
      f32x4 u = acc[i][jj + 2];
      int col = g0 + wc * 32 + jj * 16 + lc;
#pragma unroll
      for (int r = 0; r < 4; r++) {
        int row = row_base + wr * 64 + i * 16 + quad * 4 + r;
        float gv = g[r], uv = u[r];
        float hh = (gv / (1.0f + __expf(-gv))) * uv;
        hidden[(size_t)row * HDIM + col] = (__bf16)hh;
      }
    }
  }
}

// ---------------- GEMM2: disp = hidden @ W2  (no atomics) ----------------
__global__ __launch_bounds__(256) void gemm2_kernel(
    const __bf16* __restrict__ hidden, const __bf16* __restrict__ w2t,
    const int* __restrict__ ctrl, __bf16* __restrict__ disp) {
  __shared__ __align__(16) __bf16 As[128 * 32];
  __shared__ __align__(16) __bf16 Bs[128 * 32];
  const int* seg = ctrl + 16;
  const int row_base = blockIdx.y * 128;
  if (row_base >= seg[NE]) return;
  int e = 0;
#pragma unroll
  for (int q = 1; q <= 7; q++) if (row_base >= seg[q]) e = q;

  const int bn0 = blockIdx.x * 128;
  const int tid = threadIdx.x;
  const int l = tid & 63;
  const int wv = tid >> 6, wr = wv >> 1, wc = wv & 1;
  const int quad = l >> 4, lc = l & 15;

  const int s0 = tid, s1 = tid + 256;
  const int am0 = s0 >> 2, am1 = s1 >> 2;
  const int koff = (tid & 3) * 8;
  const __bf16* ga0 = hidden + (size_t)(row_base + am0) * HDIM + koff;
  const __bf16* ga1 = hidden + (size_t)(row_base + am1) * HDIM + koff;
  const __bf16* wb = w2t + (size_t)e * DIM * HDIM;
  const __bf16* gb0 = wb + (size_t)(bn0 + am0) * HDIM + koff;
  const __bf16* gb1 = wb + (size_t)(bn0 + am1) * HDIM + koff;

  const f32x4 fzero = {0.f, 0.f, 0.f, 0.f};
  f32x4 acc[4][4];
#pragma unroll
  for (int i = 0; i < 4; i++)
#pragma unroll
    for (int j = 0; j < 4; j++) acc[i][j] = fzero;

  const bf16x8* Af = (const bf16x8*)As;
  const bf16x8* Bf = (const bf16x8*)Bs;
  const int arow = wr * 64 + lc;
  const int brow = wc * 64 + lc;

  for (int kt = 0; kt < HDIM; kt += 32) {
    async_copy16(ga0 + kt, As + (size_t)s0 * 8);
    async_copy16(ga1 + kt, As + (size_t)s1 * 8);
    async_copy16(gb0 + kt, Bs + (size_t)s0 * 8);
    async_copy16(gb1 + kt, Bs + (size_t)s1 * 8);
    __syncthreads();
    bf16x8 a[4], b[4];
#pragma unroll
    for (int i = 0; i < 4; i++) a[i] = Af[(arow + i * 16) * 4 + quad];
#pragma unroll
    for (int j = 0; j < 4; j++) b[j] = Bf[(brow + j * 16) * 4 + quad];
#pragma unroll
    for (int i = 0; i < 4; i++)
#pragma unroll
      for (int j = 0; j < 4; j++)
        acc[i][j] = __builtin_amdgcn_mfma_f32_16x16x32_bf16(a[i], b[j], acc[i][j], 0, 0, 0);
    __syncthreads();
  }

#pragma unroll
  for (int i = 0; i < 4; i++) {
    int rbase = row_base + wr * 64 + i * 16 + quad * 4;
#pragma unroll
    for (int j = 0; j < 4; j++) {
      int col = bn0 + wc * 64 + j * 16 + lc;
#pragma unroll
      for (int r = 0; r < 4; r++)
        disp[(size_t)(rbase + r) * DIM + col] = (__bf16)acc[i][j][r];
    }
  }
}

// ---------------- combine: out[t] = w0*disp[p0] + w1*disp[p1] ----------------
__global__ __launch_bounds__(256) void combine_kernel(
    const __bf16* __restrict__ disp, const int* __restrict__ pos_of,
    const float* __restrict__ tw, float* __restrict__ out) {
  const int t = blockIdx.x;
  const int tid = threadIdx.x;
  const int p0 = pos_of[t * 2], p1 = pos_of[t * 2 + 1];
  const float w0 = tw[t * 2], w1 = tw[t * 2 + 1];
  bf16x4_t d0 = ((const bf16x4_t*)(disp + (size_t)p0 * DIM))[tid];
  bf16x4_t d1 = ((const bf16x4_t*)(disp + (size_t)p1 * DIM))[tid];
  f32x4 o;
#pragma unroll
  for (int i = 0; i < 4; i++)
    o[i] = w0 * (float)d0[i] + w1 * (float)d1[i];
  ((f32x4*)(out + (size_t)t * DIM))[tid] = o;
}

extern "C" void kernel_launch(void* const* d_in, const int* in_sizes, int n_in,
                              void* d_out, int out_size, void* d_ws, size_t ws_size,
                              hipStream_t stream) {
  const float* x   = (const float*)d_in[0];
  const float* rt  = (const float*)d_in[1];
  const float* w13 = (const float*)d_in[2];
  const float* w2  = (const float*)d_in[3];
  float* out = (float*)d_out;
  char* ws = (char*)d_ws;

  __bf16* xb      = (__bf16*)(ws + OFF_XB);
  __bf16* w13t    = (__bf16*)(ws + OFF_W13T);
  __bf16* w2t     = (__bf16*)(ws + OFF_W2T);
  __bf16* hidden  = (__bf16*)(ws + OFF_HID);
  __bf16* disp    = (__bf16*)(ws + OFF_DISP);
  int*    tidx    = (int*)(ws + OFF_TIDX);
  float*  tw      = (float*)(ws + OFF_TW);
  int*    pos_of  = (int*)(ws + OFF_POS);
  int*    tokid   = (int*)(ws + OFF_TOKID);
  float*  roww    = (float*)(ws + OFF_ROWW);
  int*    ctrl    = (int*)(ws + OFF_CTRL);

  hipMemsetAsync(ctrl, 0, 128, stream);

  hipLaunchKernelGGL(router_kernel, dim3(TOKENS), dim3(256), 0, stream,
                     x, rt, xb, tidx, tw);
  hipLaunchKernelGGL(transpose_kernel, dim3(N13 / 64, DIM / 32, NE), dim3(256), 0, stream,
                     w13, w13t, DIM, N13);
  hipLaunchKernelGGL(transpose_kernel, dim3(DIM / 64, HDIM / 32, NE), dim3(256), 0, stream,
                     w2, w2t, HDIM, DIM);
  hipLaunchKernelGGL(histo_kernel, dim3(TOKENS * 2 / 256), dim3(256), 0, stream, tidx, ctrl);
  hipLaunchKernelGGL(scan_pad_kernel, dim3(1), dim3(256), 0, stream, ctrl, tokid, roww);
  hipLaunchKernelGGL(scatter_kernel, dim3(TOKENS * 2 / 256), dim3(256), 0, stream,
                     tidx, tw, ctrl, tokid, roww, pos_of);
  hipLaunchKernelGGL(gemm1_kernel, dim3(HDIM / 64, CAPT), dim3(256), 0, stream,
                     xb, w13t, tokid, ctrl, hidden);
  hipLaunchKernelGGL(gemm2_kernel, dim3(DIM / 128, CAPT), dim3(256), 0, stream,
                     hidden, w2t, ctrl, disp);
  hipLaunchKernelGGL(combine_kernel, dim3(TOKENS), dim3(256), 0, stream,
                     disp, pos_of, tw, out);
}